// Round 6
// baseline (997.629 us; speedup 1.0000x reference)
//
#include <hip/hip_runtime.h>
#include <hip/hip_bf16.h>
#include <math.h>

#define BATCH 32
#define SEQ   512
#define VOCAB 32000
#define EMB   256
#define HID   512
#define G3    1536   // 3*HID

#define SENT  0xAAAAAAAAu   // poison pattern = publication sentinel

// =====================================================================
// Kernel 1: xp[m][g] = emb_table[input[m]][:] . w_ih[g][:] + b_ih[g]
// M = B*T = 16384, N = 1536, K = 256.  Tiled fp32 GEMM, 128x128 tile,
// BK=32, 256 threads, 8x8 micro-tile per thread.  fp32 vector ALU
// (no fp32-input MFMA on CDNA4).
// =====================================================================
#define K1_BM 128
#define K1_BN 128
#define K1_BK 32

__global__ __launch_bounds__(256) void xproj_kernel(
    const int* __restrict__ input,        // [B*T]
    const float* __restrict__ emb,        // [V][E]
    const float* __restrict__ w_ih,       // [G3][E]
    const float* __restrict__ b_ih,       // [G3]
    float* __restrict__ xp)               // [B*T][G3]
{
    // +4 pad: row stride 132 floats = 528 B (16B-divisible, float4-safe)
    __shared__ float As[K1_BK][K1_BM + 4];
    __shared__ float Bs[K1_BK][K1_BN + 4];
    __shared__ int   rows[K1_BM];

    const int tid = threadIdx.x;
    const int m0 = (int)blockIdx.x * K1_BM;
    const int n0 = (int)blockIdx.y * K1_BN;

    if (tid < K1_BM) rows[tid] = input[m0 + tid];
    __syncthreads();

    const int tx = tid & 15;
    const int ty = tid >> 4;

    float acc[8][8];
#pragma unroll
    for (int i = 0; i < 8; ++i)
#pragma unroll
        for (int j = 0; j < 8; ++j) acc[i][j] = 0.f;

    for (int k0 = 0; k0 < EMB; k0 += K1_BK) {
#pragma unroll
        for (int i = 0; i < 4; ++i) {
            int v  = tid + i * 256;          // 1024 float4 slots
            int r  = v >> 3;                 // row 0..127
            int kb = v & 7;                  // float4 within BK
            float4 a4 = *(const float4*)(emb + (size_t)rows[r] * EMB + k0 + kb * 4);
            As[kb * 4 + 0][r] = a4.x;
            As[kb * 4 + 1][r] = a4.y;
            As[kb * 4 + 2][r] = a4.z;
            As[kb * 4 + 3][r] = a4.w;
        }
#pragma unroll
        for (int i = 0; i < 4; ++i) {
            int v  = tid + i * 256;
            int r  = v >> 3;
            int kb = v & 7;
            float4 b4 = *(const float4*)(w_ih + (size_t)(n0 + r) * EMB + k0 + kb * 4);
            Bs[kb * 4 + 0][r] = b4.x;
            Bs[kb * 4 + 1][r] = b4.y;
            Bs[kb * 4 + 2][r] = b4.z;
            Bs[kb * 4 + 3][r] = b4.w;
        }
        __syncthreads();

#pragma unroll
        for (int kk = 0; kk < K1_BK; ++kk) {
            float4 a0 = *(const float4*)&As[kk][ty * 8];
            float4 a1 = *(const float4*)&As[kk][ty * 8 + 4];
            float4 b0 = *(const float4*)&Bs[kk][tx * 8];
            float4 b1 = *(const float4*)&Bs[kk][tx * 8 + 4];
            float a[8] = {a0.x, a0.y, a0.z, a0.w, a1.x, a1.y, a1.z, a1.w};
            float bb[8] = {b0.x, b0.y, b0.z, b0.w, b1.x, b1.y, b1.z, b1.w};
#pragma unroll
            for (int i = 0; i < 8; ++i)
#pragma unroll
                for (int j = 0; j < 8; ++j)
                    acc[i][j] = fmaf(a[i], bb[j], acc[i][j]);
        }
        __syncthreads();
    }

#pragma unroll
    for (int i = 0; i < 8; ++i) {
        int m = m0 + ty * 8 + i;
        size_t base = (size_t)m * G3 + n0 + tx * 8;
#pragma unroll
        for (int j = 0; j < 8; j += 4) {
            float4 v;
            v.x = acc[i][j + 0] + b_ih[n0 + tx * 8 + j + 0];
            v.y = acc[i][j + 1] + b_ih[n0 + tx * 8 + j + 1];
            v.z = acc[i][j + 2] + b_ih[n0 + tx * 8 + j + 2];
            v.w = acc[i][j + 3] + b_ih[n0 + tx * 8 + j + 3];
            *(float4*)(xp + base + j) = v;
        }
    }
}

// =====================================================================
// Kernel 2: persistent GRU recurrence with DATA-SPIN publication.
// 256 blocks = 32 chains x 8 row-slices of 64 hidden units.
// Each block holds its w_hh slice (192 rows x 512 k, fp32 = 384 KB)
// register-stationary: 512 thr x 192 weight VGPRs.  Thread (wave kq,
// lane): rows {r,z,n} of hidden idx s*64+lane, k in [kq*64, kq*64+64).
//
// Publication protocol (NO flags, NO fences):
//   out[b][t][:] IS h_{t+1}.  Writer wave0 stores hnew via relaxed
//   AGENT-scope atomic stores (coherence-point visible cross-XCD).
//   Reader thread tid polls out[b][t-1][tid] -- exactly the element it
//   consumes -- until bits != SENT; the successful poll RETURNS the
//   data (per-element data dependence: no fence, no second load).
//   `out` is memset to SENT before launch (self-reliant).  A computed
//   hnew bit-equal to SENT is nudged 1 ulp (~1e-13) -- removes the
//   only hang mode.  Watchdog (1<<15 polls ~1ms/step) converts any
//   protocol failure into a finite wrong answer, never a hang.
//
// Per step: prefetch xp (hides under poll) -> poll own element ->
// hl[tid]=v -> B1 -> 192 FMAs -> part -> B2 -> wave0: reduce (own
// partials stay in regs), gates, publish.  No tail barrier.
// Race audit: only wave kq==s overlaps wave0's hprev read at
// hl[s*64+lane]; its t+1 poll is gated by own wave0's publish, which
// is data-dependent on (ordered after) that hprev read.  Safe.
// =====================================================================
__global__ __launch_bounds__(512, 2) void gru_kernel(
    const float* __restrict__ xp,       // [B*T][G3]
    const float* __restrict__ hidden,   // [B][HID]
    const float* __restrict__ w_hh,     // [G3][HID]
    const float* __restrict__ b_hh,     // [G3]
    float* __restrict__ out,            // [B][T][HID]  (= h chain, SENT-filled)
    float* __restrict__ hlast)          // [B][HID]
{
    const int tid  = threadIdx.x;
    const int kq   = tid >> 6;     // wave id 0..7 -> k chunk
    const int lane = tid & 63;     // hidden index within slice

    const int raw = (int)blockIdx.x;
    const int x = raw & 7;
    const int k = raw >> 3;        // 0..31
    const int b = x * 4 + (k >> 3);
    const int s = k & 7;

    // ---- one-time register-stationary weight load ----
    float4 Wr[16], Wz[16], Wn[16];
    {
        const float* pr = w_hh + (size_t)(s * 64 + lane) * HID + kq * 64;
        const float* pz = pr + (size_t)HID * HID;
        const float* pn = pz + (size_t)HID * HID;
#pragma unroll
        for (int j = 0; j < 16; ++j) {
            Wr[j] = ((const float4*)pr)[j];
            Wz[j] = ((const float4*)pz)[j];
            Wn[j] = ((const float4*)pn)[j];
        }
    }
    const float bhr = b_hh[s * 64 + lane];
    const float bhz = b_hh[512 + s * 64 + lane];
    const float bhn = b_hh[1024 + s * 64 + lane];

    __shared__ float hl[HID];
    __shared__ float part[3][8][64];

    for (int t = 0; t < SEQ; ++t) {
        // ---- prefetch xp for THIS step (independent of h_t) ----
        float xr = 0.f, xz = 0.f, xn = 0.f;
        if (kq == 0) {
            size_t xbase = ((size_t)b * SEQ + t) * G3 + s * 64 + lane;
            xr = xp[xbase];
            xz = xp[xbase + 512];
            xn = xp[xbase + 1024];
        }
        __builtin_amdgcn_sched_barrier(0);   // keep loads above the poll

        // ---- data-spin: poll own h element (the poll IS the load) ----
        float hv;
        if (t == 0) {
            hv = hidden[b * HID + tid];
        } else {
            const unsigned int* src = (const unsigned int*)
                (out + ((size_t)b * SEQ + (t - 1)) * HID + tid);
            unsigned int u = __hip_atomic_load(src, __ATOMIC_RELAXED,
                                               __HIP_MEMORY_SCOPE_AGENT);
            int guard = 0;
            while (u == SENT && ++guard < (1 << 15)) {   // ~1ms watchdog
                __builtin_amdgcn_s_sleep(1);
                u = __hip_atomic_load(src, __ATOMIC_RELAXED,
                                      __HIP_MEMORY_SCOPE_AGENT);
            }
            hv = __uint_as_float(u);
        }
        hl[tid] = hv;
        __syncthreads();                     // B1: hl complete

        // ---- partial dots over this wave's k chunk ----
        float ar = 0.f, az = 0.f, an = 0.f;
        const float* hp = &hl[kq * 64];
#pragma unroll
        for (int j = 0; j < 16; ++j) {
            float4 h4 = ((const float4*)hp)[j];
            ar = fmaf(Wr[j].x, h4.x, ar); ar = fmaf(Wr[j].y, h4.y, ar);
            ar = fmaf(Wr[j].z, h4.z, ar); ar = fmaf(Wr[j].w, h4.w, ar);
            az = fmaf(Wz[j].x, h4.x, az); az = fmaf(Wz[j].y, h4.y, az);
            az = fmaf(Wz[j].z, h4.z, az); az = fmaf(Wz[j].w, h4.w, az);
            an = fmaf(Wn[j].x, h4.x, an); an = fmaf(Wn[j].y, h4.y, an);
            an = fmaf(Wn[j].z, h4.z, an); an = fmaf(Wn[j].w, h4.w, an);
        }
        if (kq != 0) {                       // wave0 keeps its own in regs
            part[0][kq][lane] = ar;
            part[1][kq][lane] = az;
            part[2][kq][lane] = an;
        }
        __syncthreads();                     // B2: parts complete

        // ---- gate math + publish on wave 0 ----
        if (kq == 0) {
            float hr = ar, hz = az, hn = an;
#pragma unroll
            for (int q = 1; q < 8; ++q) {
                hr += part[0][q][lane];
                hz += part[1][q][lane];
                hn += part[2][q][lane];
            }
            float r = 1.f / (1.f + expf(-(xr + hr + bhr)));
            float z = 1.f / (1.f + expf(-(xz + hz + bhz)));
            float n = tanhf(xn + r * (hn + bhn));
            float hprev = hl[s * 64 + lane];      // read BEFORE publish
            float hnew = (1.f - z) * n + z * hprev;

            // sentinel-collision nudge: 1 ulp at ~1e-13, below any tol
            if (__float_as_uint(hnew) == SENT)
                hnew = __uint_as_float(SENT + 1u);

            __hip_atomic_store((unsigned int*)
                (out + ((size_t)b * SEQ + t) * HID + s * 64 + lane),
                __float_as_uint(hnew), __ATOMIC_RELAXED,
                __HIP_MEMORY_SCOPE_AGENT);

            if (t == SEQ - 1) hlast[b * HID + s * 64 + lane] = hnew;
        }
        // no tail barrier (see race audit in header comment)
    }
}

// =====================================================================
extern "C" void kernel_launch(void* const* d_in, const int* in_sizes, int n_in,
                              void* d_out, int out_size, void* d_ws, size_t ws_size,
                              hipStream_t stream) {
    const int*   input  = (const int*)d_in[0];
    const float* hidden = (const float*)d_in[1];   // [1][B][H]
    const float* emb    = (const float*)d_in[3];
    const float* w_ih   = (const float*)d_in[4];
    const float* w_hh   = (const float*)d_in[5];
    const float* b_ih   = (const float*)d_in[6];
    const float* b_hh   = (const float*)d_in[7];

    float* out   = (float*)d_out;
    float* hlast = out + (size_t)BATCH * SEQ * HID;

    // ws layout: xp[B*T*G3] f32 only (~96.3 MB)
    float* xp = (float*)d_ws;

    // Self-reliant sentinel init of the publication buffer (~5 us),
    // stream-ordered before gru.
    hipMemsetAsync(out, 0xAA, (size_t)BATCH * SEQ * HID * sizeof(float), stream);

    dim3 g1(BATCH * SEQ / K1_BM, G3 / K1_BN);   // 128 x 12
    xproj_kernel<<<g1, 256, 0, stream>>>(input, emb, w_ih, b_ih, xp);

    // Cooperative launch guarantees co-residency of all 256 blocks (the
    // spin protocol requires it) and errors loudly if they don't fit.
    // Under graph capture use a plain launch (256 blocks <= 256 CUs =>
    // all resident; the non-captured correctness call proves it via the
    // cooperative path first).
    hipStreamCaptureStatus cs = hipStreamCaptureStatusNone;
    (void)hipStreamGetCaptureInfo(stream, &cs, nullptr);
    if (cs == hipStreamCaptureStatusActive) {
        gru_kernel<<<256, 512, 0, stream>>>(xp, hidden, w_hh, b_hh, out, hlast);
    } else {
        const float* xp_c = xp;
        void* args[] = {(void*)&xp_c, (void*)&hidden, (void*)&w_hh, (void*)&b_hh,
                        (void*)&out, (void*)&hlast};
        hipError_t err = hipLaunchCooperativeKernel((const void*)gru_kernel,
                                                    dim3(256), dim3(512),
                                                    args, 0, stream);
        if (err != hipSuccess) {
            gru_kernel<<<256, 512, 0, stream>>>(xp, hidden, w_hh, b_hh, out, hlast);
        }
    }
}